// Round 1
// baseline (361.999 us; speedup 1.0000x reference)
//
#include <hip/hip_runtime.h>
#include <math.h>

#define NB   1024
#define NACT 256
#define DIM  256
#define HDIM 512
#define ADIM 512

#define BM 32
#define BN 64
#define BK 16

// ---------------- GEMM1: H = relu(concat(E, hstate, Q) @ W1 + b1) ----------------
__global__ __launch_bounds__(256) void gemm1_fused(
    const int* __restrict__ e, const int* __restrict__ q,
    const float* __restrict__ hstate,
    const float* __restrict__ ent, const float* __restrict__ rel,
    const float* __restrict__ W1, const float* __restrict__ b1,
    float* __restrict__ H)
{
    __shared__ float As[BK][BM + 1];
    __shared__ float Bs[BK][BN];
    const int tid  = threadIdx.x;
    const int col0 = blockIdx.x * BN;
    const int row0 = blockIdx.y * BM;
    const int tx = tid & 15;
    const int ty = tid >> 4;
    float acc[2][4] = {};

    for (int k0 = 0; k0 < 2 * DIM + HDIM; k0 += BK) {
        // A tile: 32 rows x 16 k, gathered. 128 threads load one float4 each.
        if (tid < 128) {
            const int m  = tid >> 2;       // 0..31
            const int k4 = tid & 3;        // float4 index in k
            const int b  = row0 + m;
            const int kb = k0 + k4 * 4;
            float4 v;
            if (kb < DIM) {
                v = *(const float4*)(ent + (size_t)e[b] * DIM + kb);
            } else if (kb < DIM + HDIM) {
                v = *(const float4*)(hstate + (size_t)b * HDIM + (kb - DIM));
            } else {
                v = *(const float4*)(rel + (size_t)q[b] * DIM + (kb - DIM - HDIM));
            }
            As[k4 * 4 + 0][m] = v.x;
            As[k4 * 4 + 1][m] = v.y;
            As[k4 * 4 + 2][m] = v.z;
            As[k4 * 4 + 3][m] = v.w;
        }
        // B tile: 16 k x 64 n, all 256 threads load one float4.
        {
            const int n4 = tid & 15;
            const int k  = tid >> 4;
            float4 v = *(const float4*)(W1 + (size_t)(k0 + k) * ADIM + col0 + n4 * 4);
            *(float4*)(&Bs[k][n4 * 4]) = v;
        }
        __syncthreads();
        #pragma unroll
        for (int kk = 0; kk < BK; ++kk) {
            const float a0  = As[kk][ty * 2 + 0];
            const float a1  = As[kk][ty * 2 + 1];
            const float b0v = Bs[kk][tx * 4 + 0];
            const float b1v = Bs[kk][tx * 4 + 1];
            const float b2v = Bs[kk][tx * 4 + 2];
            const float b3v = Bs[kk][tx * 4 + 3];
            acc[0][0] += a0 * b0v; acc[0][1] += a0 * b1v; acc[0][2] += a0 * b2v; acc[0][3] += a0 * b3v;
            acc[1][0] += a1 * b0v; acc[1][1] += a1 * b1v; acc[1][2] += a1 * b2v; acc[1][3] += a1 * b3v;
        }
        __syncthreads();
    }
    #pragma unroll
    for (int r = 0; r < 2; ++r) {
        const int row = row0 + ty * 2 + r;
        const int col = col0 + tx * 4;
        float4 o;
        o.x = fmaxf(acc[r][0] + b1[col + 0], 0.0f);
        o.y = fmaxf(acc[r][1] + b1[col + 1], 0.0f);
        o.z = fmaxf(acc[r][2] + b1[col + 2], 0.0f);
        o.w = fmaxf(acc[r][3] + b1[col + 3], 0.0f);
        *(float4*)(H + (size_t)row * ADIM + col) = o;
    }
}

// ---------------- GEMM2: X2 = H @ W2 + b2 ----------------
__global__ __launch_bounds__(256) void gemm2_kernel(
    const float* __restrict__ Hm, const float* __restrict__ W2,
    const float* __restrict__ b2, float* __restrict__ X2)
{
    __shared__ float As[BK][BM + 1];
    __shared__ float Bs[BK][BN];
    const int tid  = threadIdx.x;
    const int col0 = blockIdx.x * BN;
    const int row0 = blockIdx.y * BM;
    const int tx = tid & 15;
    const int ty = tid >> 4;
    float acc[2][4] = {};

    for (int k0 = 0; k0 < ADIM; k0 += BK) {
        if (tid < 128) {
            const int m  = tid >> 2;
            const int k4 = tid & 3;
            const int b  = row0 + m;
            const int kb = k0 + k4 * 4;
            float4 v = *(const float4*)(Hm + (size_t)b * ADIM + kb);
            As[k4 * 4 + 0][m] = v.x;
            As[k4 * 4 + 1][m] = v.y;
            As[k4 * 4 + 2][m] = v.z;
            As[k4 * 4 + 3][m] = v.w;
        }
        {
            const int n4 = tid & 15;
            const int k  = tid >> 4;
            float4 v = *(const float4*)(W2 + (size_t)(k0 + k) * ADIM + col0 + n4 * 4);
            *(float4*)(&Bs[k][n4 * 4]) = v;
        }
        __syncthreads();
        #pragma unroll
        for (int kk = 0; kk < BK; ++kk) {
            const float a0  = As[kk][ty * 2 + 0];
            const float a1  = As[kk][ty * 2 + 1];
            const float b0v = Bs[kk][tx * 4 + 0];
            const float b1v = Bs[kk][tx * 4 + 1];
            const float b2v = Bs[kk][tx * 4 + 2];
            const float b3v = Bs[kk][tx * 4 + 3];
            acc[0][0] += a0 * b0v; acc[0][1] += a0 * b1v; acc[0][2] += a0 * b2v; acc[0][3] += a0 * b3v;
            acc[1][0] += a1 * b0v; acc[1][1] += a1 * b1v; acc[1][2] += a1 * b2v; acc[1][3] += a1 * b3v;
        }
        __syncthreads();
    }
    #pragma unroll
    for (int r = 0; r < 2; ++r) {
        const int row = row0 + ty * 2 + r;
        const int col = col0 + tx * 4;
        float4 o;
        o.x = acc[r][0] + b2[col + 0];
        o.y = acc[r][1] + b2[col + 1];
        o.z = acc[r][2] + b2[col + 2];
        o.w = acc[r][3] + b2[col + 3];
        *(float4*)(X2 + (size_t)row * ADIM + col) = o;
    }
}

// ------------- scores + masked softmax + entropy, one block per batch row -------------
__global__ __launch_bounds__(256) void scores_kernel(
    const int* __restrict__ r_space, const int* __restrict__ e_space,
    const float* __restrict__ amask,
    const float* __restrict__ ent, const float* __restrict__ rel,
    const float* __restrict__ X2,
    float* __restrict__ dist_out, float* __restrict__ ent_out)
{
    const int b   = blockIdx.x;
    const int tid = threadIdx.x;
    const int wave = tid >> 6;
    const int lane = tid & 63;

    __shared__ float xs[ADIM];     // X2 row
    __shared__ float sc[NACT];     // raw scores
    __shared__ float red[8];

    if (tid < ADIM / 4)
        ((float4*)xs)[tid] = ((const float4*)(X2 + (size_t)b * ADIM))[tid];
    __syncthreads();

    const float4 xr = ((const float4*)xs)[lane];          // xs[lane*4 .. +4)
    const float4 xe = ((const float4*)(xs + DIM))[lane];  // xs[256 + lane*4 ..)

    // each wave computes 64 actions; per action, 64 lanes do a coalesced 512-dot
    for (int a = wave * 64; a < wave * 64 + 64; ++a) {
        const int r  = r_space[(size_t)b * NACT + a];
        const int ei = e_space[(size_t)b * NACT + a];
        const float4 rv = ((const float4*)(rel + (size_t)r  * DIM))[lane];
        const float4 ev = ((const float4*)(ent + (size_t)ei * DIM))[lane];
        float p = rv.x * xr.x + rv.y * xr.y + rv.z * xr.z + rv.w * xr.w
                + ev.x * xe.x + ev.y * xe.y + ev.z * xe.z + ev.w * xe.w;
        #pragma unroll
        for (int off = 32; off; off >>= 1) p += __shfl_xor(p, off);
        if (lane == 0) sc[a] = p;
    }
    __syncthreads();

    // masked score for this thread's action
    const float m = amask[(size_t)b * NACT + tid];
    const float s = sc[tid] - (1.0f - m) * 1e31f;

    // block max
    float mx = s;
    #pragma unroll
    for (int off = 32; off; off >>= 1) mx = fmaxf(mx, __shfl_xor(mx, off));
    if (lane == 0) red[wave] = mx;
    __syncthreads();
    mx = fmaxf(fmaxf(red[0], red[1]), fmaxf(red[2], red[3]));

    const float ex = expf(s - mx);
    float sum = ex;
    #pragma unroll
    for (int off = 32; off; off >>= 1) sum += __shfl_xor(sum, off);
    if (lane == 0) red[4 + wave] = sum;
    __syncthreads();
    sum = (red[4] + red[5]) + (red[6] + red[7]);

    const float d = ex / sum;
    dist_out[(size_t)b * NACT + tid] = d;

    // entropy term: -sum d * log(max(d, 1e-20))
    float t = d * logf(fmaxf(d, 1e-20f));
    #pragma unroll
    for (int off = 32; off; off >>= 1) t += __shfl_xor(t, off);
    if (lane == 0) red[wave] = t;
    __syncthreads();
    if (tid == 0) ent_out[b] = -((red[0] + red[1]) + (red[2] + red[3]));
}

extern "C" void kernel_launch(void* const* d_in, const int* in_sizes, int n_in,
                              void* d_out, int out_size, void* d_ws, size_t ws_size,
                              hipStream_t stream) {
    const int*   e       = (const int*)d_in[0];
    const int*   q       = (const int*)d_in[1];
    const float* hstate  = (const float*)d_in[2];
    const int*   r_space = (const int*)d_in[3];
    const int*   e_space = (const int*)d_in[4];
    const float* amask   = (const float*)d_in[5];
    const float* ent     = (const float*)d_in[6];
    const float* rel     = (const float*)d_in[7];
    const float* W1      = (const float*)d_in[8];
    const float* b1      = (const float*)d_in[9];
    const float* W2      = (const float*)d_in[10];
    const float* b2      = (const float*)d_in[11];

    float* H  = (float*)d_ws;                    // [NB, ADIM] = 2 MB
    float* X2 = H + (size_t)NB * ADIM;           // [NB, ADIM] = 2 MB
    float* dist = (float*)d_out;                 // [NB, NACT]
    float* entr = dist + (size_t)NB * NACT;      // [NB]

    gemm1_fused <<<dim3(ADIM / BN, NB / BM), 256, 0, stream>>>(e, q, hstate, ent, rel, W1, b1, H);
    gemm2_kernel<<<dim3(ADIM / BN, NB / BM), 256, 0, stream>>>(H, W2, b2, X2);
    scores_kernel<<<NB, 256, 0, stream>>>(r_space, e_space, amask, ent, rel, X2, dist, entr);
}

// Round 2
// 277.964 us; speedup vs baseline: 1.3023x; 1.3023x over previous
//
#include <hip/hip_runtime.h>
#include <math.h>

#define NB   1024
#define NACT 256
#define DIM  256
#define HDIM 512
#define ADIM 512
#define KTOT 1024          // 2*DIM + HDIM

#define BM 64
#define BN 64
#define BK 32
#define LDA 68             // BM + 4 pad, keeps rows 16B-aligned (272 B)
#define LDB 68

// ---------------- GEMM1 split-K: Hraw += concat(E, hstate, Q) @ W1 ----------------
// blockIdx.z = K-chunk (256 wide). Chunk 0 = ent gather, 1,2 = hstate, 3 = rel gather.
__global__ __launch_bounds__(256) void gemm1_splitk(
    const int* __restrict__ e, const int* __restrict__ q,
    const float* __restrict__ hstate,
    const float* __restrict__ ent, const float* __restrict__ rel,
    const float* __restrict__ W1, float* __restrict__ Hraw)
{
    __shared__ float As[BK][LDA];
    __shared__ float Bs[BK][LDB];
    const int tid  = threadIdx.x;
    const int col0 = blockIdx.x * BN;
    const int row0 = blockIdx.y * BM;
    const int kc   = blockIdx.z;          // 0..3
    const int tx4  = (tid & 15) * 4;
    const int ty4  = (tid >> 4) * 4;
    float acc[4][4] = {};

    for (int k0 = 0; k0 < 256; k0 += BK) {
        const int kglob = kc * 256 + k0;
        // ---- stage A: 64 rows x 32 k (transposed into As[k][m]) ----
        #pragma unroll
        for (int s = 0; s < 2; ++s) {
            const int idx = tid * 2 + s;          // 0..511
            const int m   = idx >> 3;             // 0..63
            const int kf  = (idx & 7) * 4;        // 0,4,..,28
            const int b   = row0 + m;
            const float* src;
            if (kc == 0)      src = ent + (size_t)e[b] * DIM + (kglob + kf);
            else if (kc == 3) src = rel + (size_t)q[b] * DIM + (kglob + kf - DIM - HDIM);
            else              src = hstate + (size_t)b * HDIM + (kglob + kf - DIM);
            const float4 v = *(const float4*)src;
            As[kf + 0][m] = v.x;
            As[kf + 1][m] = v.y;
            As[kf + 2][m] = v.z;
            As[kf + 3][m] = v.w;
        }
        // ---- stage B: 32 k x 64 n ----
        #pragma unroll
        for (int s = 0; s < 2; ++s) {
            const int idx = tid * 2 + s;          // 0..511
            const int k   = idx >> 4;             // 0..31
            const int n4  = (idx & 15) * 4;       // 0..60
            const float4 v = *(const float4*)(W1 + (size_t)(kglob + k) * ADIM + col0 + n4);
            *(float4*)(&Bs[k][n4]) = v;
        }
        __syncthreads();
        #pragma unroll
        for (int kk = 0; kk < BK; ++kk) {
            const float4 a4 = *(const float4*)(&As[kk][ty4]);
            const float4 b4 = *(const float4*)(&Bs[kk][tx4]);
            const float a[4] = {a4.x, a4.y, a4.z, a4.w};
            const float bb[4] = {b4.x, b4.y, b4.z, b4.w};
            #pragma unroll
            for (int i = 0; i < 4; ++i)
                #pragma unroll
                for (int j = 0; j < 4; ++j)
                    acc[i][j] += a[i] * bb[j];
        }
        __syncthreads();
    }
    #pragma unroll
    for (int i = 0; i < 4; ++i)
        #pragma unroll
        for (int j = 0; j < 4; ++j)
            atomicAdd(&Hraw[(size_t)(row0 + ty4 + i) * ADIM + col0 + tx4 + j], acc[i][j]);
}

// ---------------- GEMM2 split-K: X2raw += relu(Hraw + b1) @ W2 ----------------
__global__ __launch_bounds__(256) void gemm2_splitk(
    const float* __restrict__ Hraw, const float* __restrict__ b1,
    const float* __restrict__ W2, float* __restrict__ X2raw)
{
    __shared__ float As[BK][LDA];
    __shared__ float Bs[BK][LDB];
    const int tid  = threadIdx.x;
    const int col0 = blockIdx.x * BN;
    const int row0 = blockIdx.y * BM;
    const int kc   = blockIdx.z;          // 0..3, chunks of 128
    const int tx4  = (tid & 15) * 4;
    const int ty4  = (tid >> 4) * 4;
    float acc[4][4] = {};

    for (int k0 = 0; k0 < 128; k0 += BK) {
        const int kglob = kc * 128 + k0;
        #pragma unroll
        for (int s = 0; s < 2; ++s) {
            const int idx = tid * 2 + s;
            const int m   = idx >> 3;
            const int kf  = (idx & 7) * 4;
            const int b   = row0 + m;
            float4 v = *(const float4*)(Hraw + (size_t)b * ADIM + kglob + kf);
            const float4 bias = *(const float4*)(b1 + kglob + kf);
            v.x = fmaxf(v.x + bias.x, 0.0f);
            v.y = fmaxf(v.y + bias.y, 0.0f);
            v.z = fmaxf(v.z + bias.z, 0.0f);
            v.w = fmaxf(v.w + bias.w, 0.0f);
            As[kf + 0][m] = v.x;
            As[kf + 1][m] = v.y;
            As[kf + 2][m] = v.z;
            As[kf + 3][m] = v.w;
        }
        #pragma unroll
        for (int s = 0; s < 2; ++s) {
            const int idx = tid * 2 + s;
            const int k   = idx >> 4;
            const int n4  = (idx & 15) * 4;
            const float4 v = *(const float4*)(W2 + (size_t)(kglob + k) * ADIM + col0 + n4);
            *(float4*)(&Bs[k][n4]) = v;
        }
        __syncthreads();
        #pragma unroll
        for (int kk = 0; kk < BK; ++kk) {
            const float4 a4 = *(const float4*)(&As[kk][ty4]);
            const float4 b4 = *(const float4*)(&Bs[kk][tx4]);
            const float a[4] = {a4.x, a4.y, a4.z, a4.w};
            const float bb[4] = {b4.x, b4.y, b4.z, b4.w};
            #pragma unroll
            for (int i = 0; i < 4; ++i)
                #pragma unroll
                for (int j = 0; j < 4; ++j)
                    acc[i][j] += a[i] * bb[j];
        }
        __syncthreads();
    }
    #pragma unroll
    for (int i = 0; i < 4; ++i)
        #pragma unroll
        for (int j = 0; j < 4; ++j)
            atomicAdd(&X2raw[(size_t)(row0 + ty4 + i) * ADIM + col0 + tx4 + j], acc[i][j]);
}

// ------------- scores + masked softmax + entropy, one block per batch row -------------
__global__ __launch_bounds__(256) void scores_kernel(
    const int* __restrict__ r_space, const int* __restrict__ e_space,
    const float* __restrict__ amask,
    const float* __restrict__ ent, const float* __restrict__ rel,
    const float* __restrict__ X2raw, const float* __restrict__ b2,
    float* __restrict__ dist_out, float* __restrict__ ent_out)
{
    const int b   = blockIdx.x;
    const int tid = threadIdx.x;
    const int wave = tid >> 6;
    const int lane = tid & 63;

    __shared__ float xs[ADIM];
    __shared__ float sc[NACT];
    __shared__ float red[8];

    if (tid < ADIM / 4) {
        float4 v = ((const float4*)(X2raw + (size_t)b * ADIM))[tid];
        const float4 bb = ((const float4*)b2)[tid];
        v.x += bb.x; v.y += bb.y; v.z += bb.z; v.w += bb.w;
        ((float4*)xs)[tid] = v;
    }
    __syncthreads();

    const float4 xr = ((const float4*)xs)[lane];
    const float4 xe = ((const float4*)(xs + DIM))[lane];

    // 4 actions in flight per wave iteration (MLP)
    for (int a0 = wave * 64; a0 < wave * 64 + 64; a0 += 4) {
        float p[4];
        #pragma unroll
        for (int i = 0; i < 4; ++i) {
            const int r  = r_space[(size_t)b * NACT + a0 + i];
            const int ei = e_space[(size_t)b * NACT + a0 + i];
            const float4 rv = ((const float4*)(rel + (size_t)r  * DIM))[lane];
            const float4 ev = ((const float4*)(ent + (size_t)ei * DIM))[lane];
            p[i] = rv.x * xr.x + rv.y * xr.y + rv.z * xr.z + rv.w * xr.w
                 + ev.x * xe.x + ev.y * xe.y + ev.z * xe.z + ev.w * xe.w;
        }
        #pragma unroll
        for (int off = 32; off; off >>= 1) {
            #pragma unroll
            for (int i = 0; i < 4; ++i) p[i] += __shfl_xor(p[i], off);
        }
        if (lane == 0) {
            sc[a0 + 0] = p[0]; sc[a0 + 1] = p[1];
            sc[a0 + 2] = p[2]; sc[a0 + 3] = p[3];
        }
    }
    __syncthreads();

    const float m = amask[(size_t)b * NACT + tid];
    const float s = sc[tid] - (1.0f - m) * 1e31f;

    float mx = s;
    #pragma unroll
    for (int off = 32; off; off >>= 1) mx = fmaxf(mx, __shfl_xor(mx, off));
    if (lane == 0) red[wave] = mx;
    __syncthreads();
    mx = fmaxf(fmaxf(red[0], red[1]), fmaxf(red[2], red[3]));

    const float ex = expf(s - mx);
    float sum = ex;
    #pragma unroll
    for (int off = 32; off; off >>= 1) sum += __shfl_xor(sum, off);
    if (lane == 0) red[4 + wave] = sum;
    __syncthreads();
    sum = (red[4] + red[5]) + (red[6] + red[7]);

    const float d = ex / sum;
    dist_out[(size_t)b * NACT + tid] = d;

    float t = d * logf(fmaxf(d, 1e-20f));
    #pragma unroll
    for (int off = 32; off; off >>= 1) t += __shfl_xor(t, off);
    if (lane == 0) red[wave] = t;
    __syncthreads();
    if (tid == 0) ent_out[b] = -((red[0] + red[1]) + (red[2] + red[3]));
}

extern "C" void kernel_launch(void* const* d_in, const int* in_sizes, int n_in,
                              void* d_out, int out_size, void* d_ws, size_t ws_size,
                              hipStream_t stream) {
    const int*   e       = (const int*)d_in[0];
    const int*   q       = (const int*)d_in[1];
    const float* hstate  = (const float*)d_in[2];
    const int*   r_space = (const int*)d_in[3];
    const int*   e_space = (const int*)d_in[4];
    const float* amask   = (const float*)d_in[5];
    const float* ent     = (const float*)d_in[6];
    const float* rel     = (const float*)d_in[7];
    const float* W1      = (const float*)d_in[8];
    const float* b1      = (const float*)d_in[9];
    const float* W2      = (const float*)d_in[10];
    const float* b2      = (const float*)d_in[11];

    float* Hraw  = (float*)d_ws;                   // [NB, ADIM]
    float* X2raw = Hraw + (size_t)NB * ADIM;       // [NB, ADIM]
    float* dist  = (float*)d_out;
    float* entr  = dist + (size_t)NB * NACT;

    hipMemsetAsync(d_ws, 0, (size_t)2 * NB * ADIM * sizeof(float), stream);

    gemm1_splitk<<<dim3(ADIM / BN, NB / BM, 4), 256, 0, stream>>>(e, q, hstate, ent, rel, W1, Hraw);
    gemm2_splitk<<<dim3(ADIM / BN, NB / BM, 4), 256, 0, stream>>>(Hraw, b1, W2, X2raw);
    scores_kernel<<<NB, 256, 0, stream>>>(r_space, e_space, amask, ent, rel, X2raw, b2, dist, entr);
}

// Round 3
// 241.059 us; speedup vs baseline: 1.5017x; 1.1531x over previous
//
#include <hip/hip_runtime.h>
#include <math.h>

#define NB   1024
#define NACT 256
#define DIM  256
#define HDIM 512
#define ADIM 512
#define KTOT 1024          // 2*DIM + HDIM
#define KSPL 8

#define BM 64
#define BN 64
#define BK 32
#define LDA 68             // BM + 4 pad, keeps rows 16B-aligned (272 B)
#define LDB 68

// ---------------- GEMM1 split-K: Hpart[kc] = X_chunk @ W1_chunk ----------------
// kc = K-chunk of 128. Segments: [0,256)=ent gather, [256,768)=hstate, [768,1024)=rel gather.
__global__ __launch_bounds__(256) void gemm1_splitk(
    const int* __restrict__ e, const int* __restrict__ q,
    const float* __restrict__ hstate,
    const float* __restrict__ ent, const float* __restrict__ rel,
    const float* __restrict__ W1, float* __restrict__ Hpart)
{
    __shared__ float As[BK][LDA];
    __shared__ float Bs[BK][LDB];
    const int tid  = threadIdx.x;
    const int col0 = blockIdx.x * BN;
    const int row0 = blockIdx.y * BM;
    const int kc   = blockIdx.z;          // 0..7
    const int kbase = kc * (KTOT / KSPL); // 0,128,...,896
    const int tx4  = (tid & 15) * 4;
    const int ty4  = (tid >> 4) * 4;
    float acc[4][4] = {};

    for (int k0 = 0; k0 < KTOT / KSPL; k0 += BK) {
        const int kglob = kbase + k0;
        // ---- stage A: 64 rows x 32 k (transposed into As[k][m]) ----
        #pragma unroll
        for (int s = 0; s < 2; ++s) {
            const int idx = tid * 2 + s;          // 0..511
            const int m   = idx >> 3;             // 0..63
            const int kf  = (idx & 7) * 4;        // 0,4,..,28
            const int b   = row0 + m;
            const int kk2 = kglob + kf;
            const float* src;
            if (kbase < DIM)             src = ent + (size_t)e[b] * DIM + kk2;
            else if (kbase < DIM + HDIM) src = hstate + (size_t)b * HDIM + (kk2 - DIM);
            else                         src = rel + (size_t)q[b] * DIM + (kk2 - DIM - HDIM);
            const float4 v = *(const float4*)src;
            As[kf + 0][m] = v.x;
            As[kf + 1][m] = v.y;
            As[kf + 2][m] = v.z;
            As[kf + 3][m] = v.w;
        }
        // ---- stage B: 32 k x 64 n ----
        #pragma unroll
        for (int s = 0; s < 2; ++s) {
            const int idx = tid * 2 + s;          // 0..511
            const int k   = idx >> 4;             // 0..31
            const int n4  = (idx & 15) * 4;       // 0..60
            const float4 v = *(const float4*)(W1 + (size_t)(kglob + k) * ADIM + col0 + n4);
            *(float4*)(&Bs[k][n4]) = v;
        }
        __syncthreads();
        #pragma unroll
        for (int kk = 0; kk < BK; ++kk) {
            const float4 a4 = *(const float4*)(&As[kk][ty4]);
            const float4 b4 = *(const float4*)(&Bs[kk][tx4]);
            const float a[4] = {a4.x, a4.y, a4.z, a4.w};
            const float bb[4] = {b4.x, b4.y, b4.z, b4.w};
            #pragma unroll
            for (int i = 0; i < 4; ++i)
                #pragma unroll
                for (int j = 0; j < 4; ++j)
                    acc[i][j] += a[i] * bb[j];
        }
        __syncthreads();
    }
    float* dst = Hpart + (size_t)kc * NB * ADIM;
    #pragma unroll
    for (int i = 0; i < 4; ++i) {
        float4 o = {acc[i][0], acc[i][1], acc[i][2], acc[i][3]};
        *(float4*)(dst + (size_t)(row0 + ty4 + i) * ADIM + col0 + tx4) = o;
    }
}

// ---------------- GEMM2 split-K: X2part[kc] = relu(sum Hpart + b1)_chunk @ W2_chunk ----------------
__global__ __launch_bounds__(256) void gemm2_splitk(
    const float* __restrict__ Hpart, const float* __restrict__ b1,
    const float* __restrict__ W2, float* __restrict__ X2part)
{
    __shared__ float As[BK][LDA];
    __shared__ float Bs[BK][LDB];
    const int tid  = threadIdx.x;
    const int col0 = blockIdx.x * BN;
    const int row0 = blockIdx.y * BM;
    const int kc   = blockIdx.z;          // 0..7, chunks of 64
    const int tx4  = (tid & 15) * 4;
    const int ty4  = (tid >> 4) * 4;
    float acc[4][4] = {};

    for (int k0 = 0; k0 < ADIM / KSPL; k0 += BK) {   // 2 iters
        const int kglob = kc * (ADIM / KSPL) + k0;
        #pragma unroll
        for (int s = 0; s < 2; ++s) {
            const int idx = tid * 2 + s;
            const int m   = idx >> 3;
            const int kf  = (idx & 7) * 4;
            const int b   = row0 + m;
            const size_t off = (size_t)b * ADIM + kglob + kf;
            float4 v = *(const float4*)(b1 + kglob + kf);
            #pragma unroll
            for (int z = 0; z < KSPL; ++z) {
                const float4 p = *(const float4*)(Hpart + (size_t)z * NB * ADIM + off);
                v.x += p.x; v.y += p.y; v.z += p.z; v.w += p.w;
            }
            v.x = fmaxf(v.x, 0.0f);
            v.y = fmaxf(v.y, 0.0f);
            v.z = fmaxf(v.z, 0.0f);
            v.w = fmaxf(v.w, 0.0f);
            As[kf + 0][m] = v.x;
            As[kf + 1][m] = v.y;
            As[kf + 2][m] = v.z;
            As[kf + 3][m] = v.w;
        }
        #pragma unroll
        for (int s = 0; s < 2; ++s) {
            const int idx = tid * 2 + s;
            const int k   = idx >> 4;
            const int n4  = (idx & 15) * 4;
            const float4 v = *(const float4*)(W2 + (size_t)(kglob + k) * ADIM + col0 + n4);
            *(float4*)(&Bs[k][n4]) = v;
        }
        __syncthreads();
        #pragma unroll
        for (int kk = 0; kk < BK; ++kk) {
            const float4 a4 = *(const float4*)(&As[kk][ty4]);
            const float4 b4 = *(const float4*)(&Bs[kk][tx4]);
            const float a[4] = {a4.x, a4.y, a4.z, a4.w};
            const float bb[4] = {b4.x, b4.y, b4.z, b4.w};
            #pragma unroll
            for (int i = 0; i < 4; ++i)
                #pragma unroll
                for (int j = 0; j < 4; ++j)
                    acc[i][j] += a[i] * bb[j];
        }
        __syncthreads();
    }
    float* dst = X2part + (size_t)kc * NB * ADIM;
    #pragma unroll
    for (int i = 0; i < 4; ++i) {
        float4 o = {acc[i][0], acc[i][1], acc[i][2], acc[i][3]};
        *(float4*)(dst + (size_t)(row0 + ty4 + i) * ADIM + col0 + tx4) = o;
    }
}

// ------------- scores + masked softmax + entropy, one block (512 thr) per batch row -------------
__global__ __launch_bounds__(512) void scores_kernel(
    const int* __restrict__ r_space, const int* __restrict__ e_space,
    const float* __restrict__ amask,
    const float* __restrict__ ent, const float* __restrict__ rel,
    const float* __restrict__ X2part, const float* __restrict__ b2,
    float* __restrict__ dist_out, float* __restrict__ ent_out)
{
    const int b    = blockIdx.x;
    const int tid  = threadIdx.x;
    const int wave = tid >> 6;     // 0..7
    const int lane = tid & 63;

    __shared__ float xs[ADIM];
    __shared__ float sc[NACT];
    __shared__ float red1[8], red2[8], red3[8];

    if (tid < ADIM / 4) {
        float4 v = ((const float4*)b2)[tid];
        #pragma unroll
        for (int z = 0; z < KSPL; ++z) {
            const float4 p = ((const float4*)(X2part + (size_t)z * NB * ADIM + (size_t)b * ADIM))[tid];
            v.x += p.x; v.y += p.y; v.z += p.z; v.w += p.w;
        }
        ((float4*)xs)[tid] = v;
    }
    __syncthreads();

    const float4 xr = ((const float4*)xs)[lane];
    const float4 xe = ((const float4*)(xs + DIM))[lane];

    // each of 8 waves handles 32 actions, 8 in flight
    const int abase = wave * 32;
    for (int a0 = abase; a0 < abase + 32; a0 += 8) {
        float p[8];
        #pragma unroll
        for (int i = 0; i < 8; ++i) {
            const int r  = r_space[(size_t)b * NACT + a0 + i];
            const int ei = e_space[(size_t)b * NACT + a0 + i];
            const float4 rv = ((const float4*)(rel + (size_t)r  * DIM))[lane];
            const float4 ev = ((const float4*)(ent + (size_t)ei * DIM))[lane];
            p[i] = rv.x * xr.x + rv.y * xr.y + rv.z * xr.z + rv.w * xr.w
                 + ev.x * xe.x + ev.y * xe.y + ev.z * xe.z + ev.w * xe.w;
        }
        #pragma unroll
        for (int off = 32; off; off >>= 1) {
            #pragma unroll
            for (int i = 0; i < 8; ++i) p[i] += __shfl_xor(p[i], off);
        }
        if (lane < 8) sc[a0 + lane] = p[lane];  // p[i] uniform across lanes after reduce? no —
        // NOTE: after butterfly, every lane holds the full sum for each i; lane i writes p[i].
    }
    __syncthreads();

    float s = -3.0e38f;
    if (tid < NACT) {
        const float m = amask[(size_t)b * NACT + tid];
        s = sc[tid] - (1.0f - m) * 1e31f;
    }

    float mx = s;
    #pragma unroll
    for (int off = 32; off; off >>= 1) mx = fmaxf(mx, __shfl_xor(mx, off));
    if (lane == 0) red1[wave] = mx;
    __syncthreads();
    mx = red1[0];
    #pragma unroll
    for (int w = 1; w < 8; ++w) mx = fmaxf(mx, red1[w]);

    const float ex = (tid < NACT) ? expf(s - mx) : 0.0f;
    float sum = ex;
    #pragma unroll
    for (int off = 32; off; off >>= 1) sum += __shfl_xor(sum, off);
    if (lane == 0) red2[wave] = sum;
    __syncthreads();
    sum = ((red2[0] + red2[1]) + (red2[2] + red2[3]))
        + ((red2[4] + red2[5]) + (red2[6] + red2[7]));

    const float d = ex / sum;
    if (tid < NACT) dist_out[(size_t)b * NACT + tid] = d;

    float t = (tid < NACT) ? d * logf(fmaxf(d, 1e-20f)) : 0.0f;
    #pragma unroll
    for (int off = 32; off; off >>= 1) t += __shfl_xor(t, off);
    if (lane == 0) red3[wave] = t;
    __syncthreads();
    if (tid == 0)
        ent_out[b] = -(((red3[0] + red3[1]) + (red3[2] + red3[3]))
                     + ((red3[4] + red3[5]) + (red3[6] + red3[7])));
}

extern "C" void kernel_launch(void* const* d_in, const int* in_sizes, int n_in,
                              void* d_out, int out_size, void* d_ws, size_t ws_size,
                              hipStream_t stream) {
    const int*   e       = (const int*)d_in[0];
    const int*   q       = (const int*)d_in[1];
    const float* hstate  = (const float*)d_in[2];
    const int*   r_space = (const int*)d_in[3];
    const int*   e_space = (const int*)d_in[4];
    const float* amask   = (const float*)d_in[5];
    const float* ent     = (const float*)d_in[6];
    const float* rel     = (const float*)d_in[7];
    const float* W1      = (const float*)d_in[8];
    const float* b1      = (const float*)d_in[9];
    const float* W2      = (const float*)d_in[10];
    const float* b2      = (const float*)d_in[11];

    float* Hpart  = (float*)d_ws;                              // [KSPL][NB][ADIM] = 16 MB
    float* X2part = Hpart + (size_t)KSPL * NB * ADIM;          // [KSPL][NB][ADIM] = 16 MB
    float* dist   = (float*)d_out;
    float* entr   = dist + (size_t)NB * NACT;

    gemm1_splitk<<<dim3(ADIM / BN, NB / BM, KSPL), 256, 0, stream>>>(e, q, hstate, ent, rel, W1, Hpart);
    gemm2_splitk<<<dim3(ADIM / BN, NB / BM, KSPL), 256, 0, stream>>>(Hpart, b1, W2, X2part);
    scores_kernel<<<NB, 512, 0, stream>>>(r_space, e_space, amask, ent, rel, X2part, b2, dist, entr);
}

// Round 4
// 237.695 us; speedup vs baseline: 1.5230x; 1.0142x over previous
//
#include <hip/hip_runtime.h>
#include <math.h>

#define NB   1024
#define NACT 256
#define DIM  256
#define HDIM 512
#define ADIM 512
#define KTOT 1024
#define KSPL 8
#define NE   100000
#define NR   400

#define BM 64
#define BN 64
#define BK 32
#define LDA 68
#define LDB 68

__device__ __forceinline__ unsigned short f2bf(float f) {
    unsigned int u = __float_as_uint(f);
    u += 0x7FFF + ((u >> 16) & 1);
    return (unsigned short)(u >> 16);
}
__device__ __forceinline__ float bf2f(unsigned short u) {
    return __uint_as_float(((unsigned int)u) << 16);
}

// ---------------- GEMM1 split-K + fused fp32->bf16 table conversion ----------------
__global__ __launch_bounds__(256) void gemm1_splitk(
    const int* __restrict__ e, const int* __restrict__ q,
    const float* __restrict__ hstate,
    const float* __restrict__ ent, const float* __restrict__ rel,
    const float* __restrict__ W1, float* __restrict__ Hpart,
    ushort* __restrict__ entbf, ushort* __restrict__ relbf)
{
    const int tid = threadIdx.x;
    // ---- fused conversion: 1024 blocks x 6250 float4 of ent, 25 float4 of rel ----
    {
        const int flat = blockIdx.x + blockIdx.y * gridDim.x
                       + blockIdx.z * gridDim.x * gridDim.y;   // 0..1023
        const float4* src = (const float4*)ent;
        ushort4* dst = (ushort4*)entbf;
        const int start = flat * 6250;
        #pragma unroll 4
        for (int j = start + tid; j < start + 6250; j += 256) {
            const float4 v = src[j];
            ushort4 o;
            o.x = f2bf(v.x); o.y = f2bf(v.y); o.z = f2bf(v.z); o.w = f2bf(v.w);
            dst[j] = o;
        }
        if (tid < 25) {
            const int j = flat * 25 + tid;
            const float4 v = ((const float4*)rel)[j];
            ushort4 o;
            o.x = f2bf(v.x); o.y = f2bf(v.y); o.z = f2bf(v.z); o.w = f2bf(v.w);
            ((ushort4*)relbf)[j] = o;
        }
    }

    __shared__ float As[BK][LDA];
    __shared__ float Bs[BK][LDB];
    const int col0 = blockIdx.x * BN;
    const int row0 = blockIdx.y * BM;
    const int kbase = blockIdx.z * (KTOT / KSPL);   // 0,128,...,896
    const int tx4 = (tid & 15) * 4;
    const int ty4 = (tid >> 4) * 4;

    // A: each thread owns row m = tid&63, k-chunks kf0 and kf0+16
    const int am  = tid & 63;
    const int kf0 = (tid >> 6) * 4;
    const float* abase;
    if (kbase < DIM)             abase = ent + (size_t)e[row0 + am] * DIM + kbase;
    else if (kbase < DIM + HDIM) abase = hstate + (size_t)(row0 + am) * HDIM + (kbase - DIM);
    else                         abase = rel + (size_t)q[row0 + am] * DIM + (kbase - DIM - HDIM);

    // B: thread covers rows kb0, kb0+16 at col n4 (64-wide)
    const int kb0 = tid >> 4;
    const float* bbase = W1 + col0 + tx4;

    float4 pa0 = *(const float4*)(abase + kf0);
    float4 pa1 = *(const float4*)(abase + kf0 + 16);
    float4 pb0 = *(const float4*)(bbase + (size_t)(kbase + kb0) * ADIM);
    float4 pb1 = *(const float4*)(bbase + (size_t)(kbase + kb0 + 16) * ADIM);

    float acc[4][4] = {};
    #pragma unroll
    for (int it = 0; it < (KTOT / KSPL) / BK; ++it) {     // 4 iters
        As[kf0 + 0][am] = pa0.x;
        As[kf0 + 1][am] = pa0.y;
        As[kf0 + 2][am] = pa0.z;
        As[kf0 + 3][am] = pa0.w;
        As[kf0 + 16][am] = pa1.x;
        As[kf0 + 17][am] = pa1.y;
        As[kf0 + 18][am] = pa1.z;
        As[kf0 + 19][am] = pa1.w;
        *(float4*)(&Bs[kb0][tx4])      = pb0;
        *(float4*)(&Bs[kb0 + 16][tx4]) = pb1;
        __syncthreads();
        if (it < (KTOT / KSPL) / BK - 1) {
            const int ko = (it + 1) * BK;
            pa0 = *(const float4*)(abase + ko + kf0);
            pa1 = *(const float4*)(abase + ko + kf0 + 16);
            pb0 = *(const float4*)(bbase + (size_t)(kbase + ko + kb0) * ADIM);
            pb1 = *(const float4*)(bbase + (size_t)(kbase + ko + kb0 + 16) * ADIM);
        }
        #pragma unroll
        for (int kk = 0; kk < BK; ++kk) {
            const float4 a4 = *(const float4*)(&As[kk][ty4]);
            const float4 b4 = *(const float4*)(&Bs[kk][tx4]);
            const float a[4]  = {a4.x, a4.y, a4.z, a4.w};
            const float bb[4] = {b4.x, b4.y, b4.z, b4.w};
            #pragma unroll
            for (int i = 0; i < 4; ++i)
                #pragma unroll
                for (int j = 0; j < 4; ++j)
                    acc[i][j] += a[i] * bb[j];
        }
        __syncthreads();
    }
    float* dst = Hpart + (size_t)blockIdx.z * NB * ADIM;
    #pragma unroll
    for (int i = 0; i < 4; ++i) {
        float4 o = {acc[i][0], acc[i][1], acc[i][2], acc[i][3]};
        *(float4*)(dst + (size_t)(row0 + ty4 + i) * ADIM + col0 + tx4) = o;
    }
}

// ---------------- reduce Hpart -> Hred with bias + relu ----------------
__global__ __launch_bounds__(256) void reduce_relu(
    const float* __restrict__ Hpart, const float* __restrict__ b1,
    float* __restrict__ Hred)
{
    const int i = blockIdx.x * 256 + threadIdx.x;       // float4 index, 131072 total
    float4 v = ((const float4*)b1)[i & 127];
    #pragma unroll
    for (int z = 0; z < KSPL; ++z) {
        const float4 p = ((const float4*)Hpart)[(size_t)z * (NB * ADIM / 4) + i];
        v.x += p.x; v.y += p.y; v.z += p.z; v.w += p.w;
    }
    v.x = fmaxf(v.x, 0.0f);
    v.y = fmaxf(v.y, 0.0f);
    v.z = fmaxf(v.z, 0.0f);
    v.w = fmaxf(v.w, 0.0f);
    ((float4*)Hred)[i] = v;
}

// ---------------- GEMM2 split-K: X2part = Hred_chunk @ W2_chunk ----------------
__global__ __launch_bounds__(256) void gemm2_splitk(
    const float* __restrict__ Hred, const float* __restrict__ W2,
    float* __restrict__ X2part)
{
    __shared__ float As[BK][LDA];
    __shared__ float Bs[BK][LDB];
    const int tid  = threadIdx.x;
    const int col0 = blockIdx.x * BN;
    const int row0 = blockIdx.y * BM;
    const int kbase = blockIdx.z * (ADIM / KSPL);   // 0,64,...,448
    const int tx4 = (tid & 15) * 4;
    const int ty4 = (tid >> 4) * 4;

    const int am  = tid & 63;
    const int kf0 = (tid >> 6) * 4;
    const float* abase = Hred + (size_t)(row0 + am) * ADIM + kbase;
    const int kb0 = tid >> 4;
    const float* bbase = W2 + col0 + tx4;

    float4 pa0 = *(const float4*)(abase + kf0);
    float4 pa1 = *(const float4*)(abase + kf0 + 16);
    float4 pb0 = *(const float4*)(bbase + (size_t)(kbase + kb0) * ADIM);
    float4 pb1 = *(const float4*)(bbase + (size_t)(kbase + kb0 + 16) * ADIM);

    float acc[4][4] = {};
    #pragma unroll
    for (int it = 0; it < (ADIM / KSPL) / BK; ++it) {    // 2 iters
        As[kf0 + 0][am] = pa0.x;
        As[kf0 + 1][am] = pa0.y;
        As[kf0 + 2][am] = pa0.z;
        As[kf0 + 3][am] = pa0.w;
        As[kf0 + 16][am] = pa1.x;
        As[kf0 + 17][am] = pa1.y;
        As[kf0 + 18][am] = pa1.z;
        As[kf0 + 19][am] = pa1.w;
        *(float4*)(&Bs[kb0][tx4])      = pb0;
        *(float4*)(&Bs[kb0 + 16][tx4]) = pb1;
        __syncthreads();
        if (it < (ADIM / KSPL) / BK - 1) {
            const int ko = (it + 1) * BK;
            pa0 = *(const float4*)(abase + ko + kf0);
            pa1 = *(const float4*)(abase + ko + kf0 + 16);
            pb0 = *(const float4*)(bbase + (size_t)(kbase + ko + kb0) * ADIM);
            pb1 = *(const float4*)(bbase + (size_t)(kbase + ko + kb0 + 16) * ADIM);
        }
        #pragma unroll
        for (int kk = 0; kk < BK; ++kk) {
            const float4 a4 = *(const float4*)(&As[kk][ty4]);
            const float4 b4 = *(const float4*)(&Bs[kk][tx4]);
            const float a[4]  = {a4.x, a4.y, a4.z, a4.w};
            const float bb[4] = {b4.x, b4.y, b4.z, b4.w};
            #pragma unroll
            for (int i = 0; i < 4; ++i)
                #pragma unroll
                for (int j = 0; j < 4; ++j)
                    acc[i][j] += a[i] * bb[j];
        }
        __syncthreads();
    }
    float* dst = X2part + (size_t)blockIdx.z * NB * ADIM;
    #pragma unroll
    for (int i = 0; i < 4; ++i) {
        float4 o = {acc[i][0], acc[i][1], acc[i][2], acc[i][3]};
        *(float4*)(dst + (size_t)(row0 + ty4 + i) * ADIM + col0 + tx4) = o;
    }
}

// ------------- scores (bf16 gathers) + masked softmax + entropy -------------
__global__ __launch_bounds__(512) void scores_kernel(
    const int* __restrict__ r_space, const int* __restrict__ e_space,
    const float* __restrict__ amask,
    const ushort* __restrict__ relbf, const ushort* __restrict__ entbf,
    const float* __restrict__ X2part, const float* __restrict__ b2,
    float* __restrict__ dist_out, float* __restrict__ ent_out)
{
    const int b    = blockIdx.x;
    const int tid  = threadIdx.x;
    const int wave = tid >> 6;
    const int lane = tid & 63;

    __shared__ float xs[ADIM];
    __shared__ float sc[NACT];
    __shared__ int   ridx[NACT];
    __shared__ int   eidx[NACT];
    __shared__ float red1[8], red2[8], red3[8];

    if (tid < NACT)       ridx[tid] = r_space[(size_t)b * NACT + tid];
    else                  eidx[tid - NACT] = e_space[(size_t)b * NACT + tid - NACT];
    if (tid < ADIM / 4) {
        float4 v = ((const float4*)b2)[tid];
        #pragma unroll
        for (int z = 0; z < KSPL; ++z) {
            const float4 p = ((const float4*)X2part)[(size_t)z * (NB * ADIM / 4) + b * (ADIM / 4) + tid];
            v.x += p.x; v.y += p.y; v.z += p.z; v.w += p.w;
        }
        ((float4*)xs)[tid] = v;
    }
    __syncthreads();

    const float4 xr = ((const float4*)xs)[lane];
    const float4 xe = ((const float4*)(xs + DIM))[lane];

    const int abase = wave * 32;
    for (int a0 = abase; a0 < abase + 32; a0 += 8) {
        ushort4 rv[8], ev[8];
        #pragma unroll
        for (int i = 0; i < 8; ++i) {
            rv[i] = ((const ushort4*)relbf)[(size_t)ridx[a0 + i] * (DIM / 4) + lane];
            ev[i] = ((const ushort4*)entbf)[(size_t)eidx[a0 + i] * (DIM / 4) + lane];
        }
        float p[8];
        #pragma unroll
        for (int i = 0; i < 8; ++i) {
            p[i] = bf2f(rv[i].x) * xr.x + bf2f(rv[i].y) * xr.y
                 + bf2f(rv[i].z) * xr.z + bf2f(rv[i].w) * xr.w
                 + bf2f(ev[i].x) * xe.x + bf2f(ev[i].y) * xe.y
                 + bf2f(ev[i].z) * xe.z + bf2f(ev[i].w) * xe.w;
        }
        #pragma unroll
        for (int off = 32; off; off >>= 1) {
            #pragma unroll
            for (int i = 0; i < 8; ++i) p[i] += __shfl_xor(p[i], off);
        }
        float out = p[0];
        #pragma unroll
        for (int i = 1; i < 8; ++i) out = (lane == i) ? p[i] : out;
        if (lane < 8) sc[a0 + lane] = out;
    }
    __syncthreads();

    float s = -3.0e38f;
    if (tid < NACT) {
        const float m = amask[(size_t)b * NACT + tid];
        s = sc[tid] - (1.0f - m) * 1e31f;
    }

    float mx = s;
    #pragma unroll
    for (int off = 32; off; off >>= 1) mx = fmaxf(mx, __shfl_xor(mx, off));
    if (lane == 0) red1[wave] = mx;
    __syncthreads();
    mx = red1[0];
    #pragma unroll
    for (int w = 1; w < 8; ++w) mx = fmaxf(mx, red1[w]);

    const float ex = (tid < NACT) ? expf(s - mx) : 0.0f;
    float sum = ex;
    #pragma unroll
    for (int off = 32; off; off >>= 1) sum += __shfl_xor(sum, off);
    if (lane == 0) red2[wave] = sum;
    __syncthreads();
    sum = ((red2[0] + red2[1]) + (red2[2] + red2[3]))
        + ((red2[4] + red2[5]) + (red2[6] + red2[7]));

    const float d = ex / sum;
    if (tid < NACT) dist_out[(size_t)b * NACT + tid] = d;

    float t = (tid < NACT) ? d * logf(fmaxf(d, 1e-20f)) : 0.0f;
    #pragma unroll
    for (int off = 32; off; off >>= 1) t += __shfl_xor(t, off);
    if (lane == 0) red3[wave] = t;
    __syncthreads();
    if (tid == 0)
        ent_out[b] = -(((red3[0] + red3[1]) + (red3[2] + red3[3]))
                     + ((red3[4] + red3[5]) + (red3[6] + red3[7])));
}

extern "C" void kernel_launch(void* const* d_in, const int* in_sizes, int n_in,
                              void* d_out, int out_size, void* d_ws, size_t ws_size,
                              hipStream_t stream) {
    const int*   e       = (const int*)d_in[0];
    const int*   q       = (const int*)d_in[1];
    const float* hstate  = (const float*)d_in[2];
    const int*   r_space = (const int*)d_in[3];
    const int*   e_space = (const int*)d_in[4];
    const float* amask   = (const float*)d_in[5];
    const float* ent     = (const float*)d_in[6];
    const float* rel     = (const float*)d_in[7];
    const float* W1      = (const float*)d_in[8];
    const float* b1      = (const float*)d_in[9];
    const float* W2      = (const float*)d_in[10];
    const float* b2      = (const float*)d_in[11];

    float* Hpart  = (float*)d_ws;                              // [8][1024][512]  16 MB
    float* X2part = Hpart + (size_t)KSPL * NB * ADIM;          // [8][1024][512]  16 MB
    float* Hred   = X2part + (size_t)KSPL * NB * ADIM;         // [1024][512]      2 MB
    ushort* entbf = (ushort*)(Hred + (size_t)NB * ADIM);       // [100000][256]   51.2 MB
    ushort* relbf = entbf + (size_t)NE * DIM;                  // [400][256]       0.2 MB
    float* dist   = (float*)d_out;
    float* entr   = dist + (size_t)NB * NACT;

    gemm1_splitk<<<dim3(ADIM / BN, NB / BM, KSPL), 256, 0, stream>>>(
        e, q, hstate, ent, rel, W1, Hpart, entbf, relbf);
    reduce_relu<<<dim3(NB * ADIM / 4 / 256), 256, 0, stream>>>(Hpart, b1, Hred);
    gemm2_splitk<<<dim3(ADIM / BN, NB / BM, KSPL), 256, 0, stream>>>(Hred, W2, X2part);
    scores_kernel<<<NB, 512, 0, stream>>>(
        r_space, e_space, amask, relbf, entbf, X2part, b2, dist, entr);
}

// Round 5
// 234.693 us; speedup vs baseline: 1.5424x; 1.0128x over previous
//
#include <hip/hip_runtime.h>
#include <math.h>

#define NB   1024
#define NACT 256
#define DIM  256
#define HDIM 512
#define ADIM 512
#define KTOT 1024
#define NE   100000
#define NR   400

typedef __attribute__((ext_vector_type(8))) short bf16x8;
typedef __attribute__((ext_vector_type(4))) float f32x4;

__device__ __forceinline__ unsigned short f2bf(float f) {
    unsigned int u = __float_as_uint(f);
    u += 0x7FFF + ((u >> 16) & 1);
    return (unsigned short)(u >> 16);
}
__device__ __forceinline__ float bf2f(unsigned short u) {
    return __uint_as_float(((unsigned int)u) << 16);
}

// ---------------- prep_stream: bf16 tables + Xbf = [E | H | Q] ----------------
// blocks 0..1023: entbf ; 1024..1027: relbf ; 1028..1091: Xbf (16 rows each)
__global__ __launch_bounds__(256) void prep_stream(
    const float* __restrict__ ent, const float* __restrict__ rel,
    const float* __restrict__ hstate,
    const int* __restrict__ e, const int* __restrict__ q,
    ushort* __restrict__ entbf, ushort* __restrict__ relbf,
    ushort* __restrict__ Xbf)
{
    const int blk = blockIdx.x, tid = threadIdx.x;
    if (blk < 1024) {
        const float4* src = (const float4*)ent;
        ushort4* dst = (ushort4*)entbf;
        const int start = blk * 6250;                 // 1024*6250 = NE*DIM/4
        for (int j = start + tid; j < start + 6250; j += 256) {
            const float4 v = src[j];
            ushort4 o = {f2bf(v.x), f2bf(v.y), f2bf(v.z), f2bf(v.w)};
            dst[j] = o;
        }
    } else if (blk < 1028) {
        const float4* src = (const float4*)rel;
        ushort4* dst = (ushort4*)relbf;
        const int start = (blk - 1024) * 6400;        // 4*6400 = NR*DIM/4
        for (int j = start + tid; j < start + 6400; j += 256) {
            const float4 v = src[j];
            ushort4 o = {f2bf(v.x), f2bf(v.y), f2bf(v.z), f2bf(v.w)};
            dst[j] = o;
        }
    } else {
        const int b0 = (blk - 1028) * 16;
        const int c = tid * 4;                        // column in the 1024-wide row
        for (int r = 0; r < 16; ++r) {
            const int b = b0 + r;
            float4 v;
            if (c < DIM)             v = *(const float4*)(ent + (size_t)e[b] * DIM + c);
            else if (c < DIM + HDIM) v = *(const float4*)(hstate + (size_t)b * HDIM + (c - DIM));
            else                     v = *(const float4*)(rel + (size_t)q[b] * DIM + (c - DIM - HDIM));
            ushort4 o = {f2bf(v.x), f2bf(v.y), f2bf(v.z), f2bf(v.w)};
            *(ushort4*)(Xbf + (size_t)b * KTOT + c) = o;
        }
    }
}

// ---------------- prep_transpose: W[K][N] fp32 -> WT[N][K] bf16 ----------------
__global__ __launch_bounds__(256) void prep_transpose(
    const float* __restrict__ W1, const float* __restrict__ W2,
    ushort* __restrict__ W1T, ushort* __restrict__ W2T)
{
    __shared__ float t[64][68];
    const int z = blockIdx.z;
    if (z && blockIdx.x >= 8) return;                 // W2 has K=512
    const int Kd = z ? 512 : 1024;
    const float* in = z ? W2 : W1;
    ushort* out = z ? W2T : W1T;
    const int k0 = blockIdx.x * 64, n0 = blockIdx.y * 64;
    const int tid = threadIdx.x;
    const int kr = tid >> 2, c = tid & 3;
    #pragma unroll
    for (int j = 0; j < 4; ++j) {
        const float4 v = *(const float4*)(in + (size_t)(k0 + kr) * ADIM + n0 + c * 16 + j * 4);
        *(float4*)&t[kr][c * 16 + j * 4] = v;
    }
    __syncthreads();
    const int nr = tid >> 2;
    ushort tmp[16];
    #pragma unroll
    for (int kk = 0; kk < 16; ++kk) tmp[kk] = f2bf(t[c * 16 + kk][nr]);
    *(uint4*)(out + (size_t)(n0 + nr) * Kd + k0 + c * 16)     = *(uint4*)&tmp[0];
    *(uint4*)(out + (size_t)(n0 + nr) * Kd + k0 + c * 16 + 8) = *(uint4*)&tmp[8];
}

// ---------------- MFMA GEMM: C[M][N] = A[M][K] @ Bt[N][K]^T (+bias, opt relu) ----------------
// 64x64 tile, 4 waves, each wave owns one 16-wide n-strip x 64 m.
template<int K, bool RELU_BF16>
__global__ __launch_bounds__(256) void gemm_mfma(
    const ushort* __restrict__ A, const ushort* __restrict__ Bt,
    const float* __restrict__ bias, ushort* __restrict__ Cbf,
    float* __restrict__ Cf, int ldc)
{
    __shared__ __align__(16) ushort Als[64][40];   // 32 k + 8 pad -> 80 B rows
    __shared__ __align__(16) ushort Bls[64][40];
    const int tid  = threadIdx.x;
    const int n0   = blockIdx.x * 64;
    const int m0   = blockIdx.y * 64;
    const int wave = tid >> 6, lane = tid & 63;
    const int q    = lane >> 4, l15 = lane & 15;
    const int sm   = tid >> 2, sc = tid & 3;       // staging: row, 16B chunk

    const uint4* ga = (const uint4*)(A  + (size_t)(m0 + sm) * K) + sc;
    const uint4* gb = (const uint4*)(Bt + (size_t)(n0 + sm) * K) + sc;

    f32x4 acc[4];
    #pragma unroll
    for (int mt = 0; mt < 4; ++mt) acc[mt] = (f32x4){0.f, 0.f, 0.f, 0.f};

    uint4 pa = ga[0], pb = gb[0];
    for (int it = 0; it < K / 32; ++it) {
        *(uint4*)&Als[sm][sc * 8] = pa;
        *(uint4*)&Bls[sm][sc * 8] = pb;
        __syncthreads();
        if (it + 1 < K / 32) {
            pa = ga[(it + 1) * 4];
            pb = gb[(it + 1) * 4];
        }
        const bf16x8 bfrag = *(const bf16x8*)&Bls[wave * 16 + l15][q * 8];
        #pragma unroll
        for (int mt = 0; mt < 4; ++mt) {
            const bf16x8 afrag = *(const bf16x8*)&Als[mt * 16 + l15][q * 8];
            acc[mt] = __builtin_amdgcn_mfma_f32_16x16x32_bf16(afrag, bfrag, acc[mt], 0, 0, 0);
        }
        __syncthreads();
    }
    const int n = n0 + wave * 16 + l15;
    const float bv = bias[n];
    #pragma unroll
    for (int mt = 0; mt < 4; ++mt) {
        #pragma unroll
        for (int r = 0; r < 4; ++r) {
            const int m = m0 + mt * 16 + q * 4 + r;
            const float v = acc[mt][r] + bv;
            if (RELU_BF16) Cbf[(size_t)m * ldc + n] = f2bf(fmaxf(v, 0.0f));
            else           Cf [(size_t)m * ldc + n] = v;
        }
    }
}

// ------------- scores (bf16 gathers) + masked softmax + entropy -------------
__global__ __launch_bounds__(512) void scores_kernel(
    const int* __restrict__ r_space, const int* __restrict__ e_space,
    const float* __restrict__ amask,
    const ushort* __restrict__ relbf, const ushort* __restrict__ entbf,
    const float* __restrict__ X2,
    float* __restrict__ dist_out, float* __restrict__ ent_out)
{
    const int b    = blockIdx.x;
    const int tid  = threadIdx.x;
    const int wave = tid >> 6;
    const int lane = tid & 63;

    __shared__ float xs[ADIM];
    __shared__ float sc[NACT];
    __shared__ int   ridx[NACT];
    __shared__ int   eidx[NACT];
    __shared__ float red1[8], red2[8], red3[8];

    if (tid < NACT) ridx[tid] = r_space[(size_t)b * NACT + tid];
    else            eidx[tid - NACT] = e_space[(size_t)b * NACT + tid - NACT];
    if (tid < ADIM / 4)
        ((float4*)xs)[tid] = ((const float4*)(X2 + (size_t)b * ADIM))[tid];
    __syncthreads();

    const float4 xr = ((const float4*)xs)[lane];
    const float4 xe = ((const float4*)(xs + DIM))[lane];

    const int abase = wave * 32;
    for (int a0 = abase; a0 < abase + 32; a0 += 8) {
        ushort4 rv[8], ev[8];
        #pragma unroll
        for (int i = 0; i < 8; ++i) {
            rv[i] = ((const ushort4*)relbf)[(size_t)ridx[a0 + i] * (DIM / 4) + lane];
            ev[i] = ((const ushort4*)entbf)[(size_t)eidx[a0 + i] * (DIM / 4) + lane];
        }
        float p[8];
        #pragma unroll
        for (int i = 0; i < 8; ++i) {
            p[i] = bf2f(rv[i].x) * xr.x + bf2f(rv[i].y) * xr.y
                 + bf2f(rv[i].z) * xr.z + bf2f(rv[i].w) * xr.w
                 + bf2f(ev[i].x) * xe.x + bf2f(ev[i].y) * xe.y
                 + bf2f(ev[i].z) * xe.z + bf2f(ev[i].w) * xe.w;
        }
        #pragma unroll
        for (int off = 32; off; off >>= 1) {
            #pragma unroll
            for (int i = 0; i < 8; ++i) p[i] += __shfl_xor(p[i], off);
        }
        float out = p[0];
        #pragma unroll
        for (int i = 1; i < 8; ++i) out = (lane == i) ? p[i] : out;
        if (lane < 8) sc[a0 + lane] = out;
    }
    __syncthreads();

    float s = -3.0e38f;
    if (tid < NACT) {
        const float m = amask[(size_t)b * NACT + tid];
        s = sc[tid] - (1.0f - m) * 1e31f;
    }

    float mx = s;
    #pragma unroll
    for (int off = 32; off; off >>= 1) mx = fmaxf(mx, __shfl_xor(mx, off));
    if (lane == 0) red1[wave] = mx;
    __syncthreads();
    mx = red1[0];
    #pragma unroll
    for (int w = 1; w < 8; ++w) mx = fmaxf(mx, red1[w]);

    const float ex = (tid < NACT) ? expf(s - mx) : 0.0f;
    float sum = ex;
    #pragma unroll
    for (int off = 32; off; off >>= 1) sum += __shfl_xor(sum, off);
    if (lane == 0) red2[wave] = sum;
    __syncthreads();
    sum = ((red2[0] + red2[1]) + (red2[2] + red2[3]))
        + ((red2[4] + red2[5]) + (red2[6] + red2[7]));

    const float d = ex / sum;
    if (tid < NACT) dist_out[(size_t)b * NACT + tid] = d;

    float t = (tid < NACT) ? d * logf(fmaxf(d, 1e-20f)) : 0.0f;
    #pragma unroll
    for (int off = 32; off; off >>= 1) t += __shfl_xor(t, off);
    if (lane == 0) red3[wave] = t;
    __syncthreads();
    if (tid == 0)
        ent_out[b] = -(((red3[0] + red3[1]) + (red3[2] + red3[3]))
                     + ((red3[4] + red3[5]) + (red3[6] + red3[7])));
}

extern "C" void kernel_launch(void* const* d_in, const int* in_sizes, int n_in,
                              void* d_out, int out_size, void* d_ws, size_t ws_size,
                              hipStream_t stream) {
    const int*   e       = (const int*)d_in[0];
    const int*   q       = (const int*)d_in[1];
    const float* hstate  = (const float*)d_in[2];
    const int*   r_space = (const int*)d_in[3];
    const int*   e_space = (const int*)d_in[4];
    const float* amask   = (const float*)d_in[5];
    const float* ent     = (const float*)d_in[6];
    const float* rel     = (const float*)d_in[7];
    const float* W1      = (const float*)d_in[8];
    const float* b1      = (const float*)d_in[9];
    const float* W2      = (const float*)d_in[10];
    const float* b2      = (const float*)d_in[11];

    ushort* Xbf   = (ushort*)d_ws;                       // 1024*1024
    ushort* W1T   = Xbf   + (size_t)NB * KTOT;           // 512*1024
    ushort* W2T   = W1T   + (size_t)ADIM * KTOT;         // 512*512
    ushort* Hbf   = W2T   + (size_t)ADIM * ADIM;         // 1024*512
    ushort* entbf = Hbf   + (size_t)NB * ADIM;           // 100000*256
    ushort* relbf = entbf + (size_t)NE * DIM;            // 400*256
    float*  X2    = (float*)(relbf + (size_t)NR * DIM);  // 1024*512 (16B-aligned)
    float*  dist  = (float*)d_out;
    float*  entr  = dist + (size_t)NB * NACT;

    prep_stream<<<1092, 256, 0, stream>>>(ent, rel, hstate, e, q, entbf, relbf, Xbf);
    prep_transpose<<<dim3(16, 8, 2), 256, 0, stream>>>(W1, W2, W1T, W2T);
    gemm_mfma<KTOT, true><<<dim3(ADIM / 64, NB / 64), 256, 0, stream>>>(
        Xbf, W1T, b1, Hbf, nullptr, ADIM);
    gemm_mfma<ADIM, false><<<dim3(ADIM / 64, NB / 64), 256, 0, stream>>>(
        Hbf, W2T, b2, nullptr, X2, ADIM);
    scores_kernel<<<NB, 512, 0, stream>>>(
        r_space, e_space, amask, relbf, entbf, X2, dist, entr);
}

// Round 6
// 227.240 us; speedup vs baseline: 1.5930x; 1.0328x over previous
//
#include <hip/hip_runtime.h>
#include <math.h>

#define NB   1024
#define NACT 256
#define DIM  256
#define HDIM 512
#define ADIM 512
#define KTOT 1024
#define NE   100000
#define NR   400
#define CONVB 1024          // conversion blocks in mega kernel

typedef __attribute__((ext_vector_type(8))) short bf16x8;
typedef __attribute__((ext_vector_type(4))) float f32x4;

__device__ __forceinline__ unsigned short f2bf(float f) {
    unsigned int u = __float_as_uint(f);
    u += 0x7FFF + ((u >> 16) & 1);
    return (unsigned short)(u >> 16);
}
__device__ __forceinline__ float bf2f(unsigned short u) {
    return __uint_as_float(((unsigned int)u) << 32 - 16);
}

// ---------------- prep_transpose: W[K][N] fp32 -> WT[N][K] bf16 ----------------
__global__ __launch_bounds__(256) void prep_transpose(
    const float* __restrict__ W1, const float* __restrict__ W2,
    ushort* __restrict__ W1T, ushort* __restrict__ W2T)
{
    __shared__ float t[64][68];
    const int z = blockIdx.z;
    if (z && blockIdx.x >= 8) return;                 // W2 has K=512
    const int Kd = z ? 512 : 1024;
    const float* in = z ? W2 : W1;
    ushort* out = z ? W2T : W1T;
    const int k0 = blockIdx.x * 64, n0 = blockIdx.y * 64;
    const int tid = threadIdx.x;
    const int kr = tid >> 2, c = tid & 3;
    #pragma unroll
    for (int j = 0; j < 4; ++j) {
        const float4 v = *(const float4*)(in + (size_t)(k0 + kr) * ADIM + n0 + c * 16 + j * 4);
        *(float4*)&t[kr][c * 16 + j * 4] = v;
    }
    __syncthreads();
    const int nr = tid >> 2;
    ushort tmp[16];
    #pragma unroll
    for (int kk = 0; kk < 16; ++kk) tmp[kk] = f2bf(t[c * 16 + kk][nr]);
    *(uint4*)(out + (size_t)(n0 + nr) * Kd + k0 + c * 16)     = *(uint4*)&tmp[0];
    *(uint4*)(out + (size_t)(n0 + nr) * Kd + k0 + c * 16 + 8) = *(uint4*)&tmp[8];
}

// ---------------- mega: blocks [0,1024) convert tables; [1024,1152) = gemm1 MFMA ----------------
// gemm1: Hbf = relu_bf16( gather[E|H|Q] @ W1T^T + b1 ), 64x64 tiles.
__global__ __launch_bounds__(256) void mega_conv_gemm1(
    const float* __restrict__ ent, const float* __restrict__ rel,
    const float* __restrict__ hstate,
    const int* __restrict__ e, const int* __restrict__ q,
    const ushort* __restrict__ W1T, const float* __restrict__ b1,
    ushort* __restrict__ entbf, ushort* __restrict__ relbf,
    ushort* __restrict__ Hbf)
{
    const int blk = blockIdx.x, tid = threadIdx.x;
    __shared__ __align__(16) ushort Als[64][40];   // 32 k + 8 pad -> 80 B rows
    __shared__ __align__(16) ushort Bls[64][40];

    if (blk < CONVB) {
        // ---- streaming fp32 -> bf16 conversion ----
        const float4* src = (const float4*)ent;
        ushort4* dst = (ushort4*)entbf;
        const int start = blk * 6250;                 // 1024*6250 = NE*DIM/4
        for (int j = start + tid; j < start + 6250; j += 256) {
            const float4 v = src[j];
            ushort4 o = {f2bf(v.x), f2bf(v.y), f2bf(v.z), f2bf(v.w)};
            dst[j] = o;
        }
        if (blk < 100) {                              // rel: 25600 float4 over 100 blocks
            const int j = blk * 256 + tid;
            const float4 v = ((const float4*)rel)[j];
            ushort4 o = {f2bf(v.x), f2bf(v.y), f2bf(v.z), f2bf(v.w)};
            ((ushort4*)relbf)[j] = o;
        }
        return;
    }

    // ---- gemm1 path ----
    const int g  = blk - CONVB;                       // 0..127
    const int n0 = (g & 7) * 64;
    const int m0 = (g >> 3) * 64;
    const int wave = tid >> 6, lane = tid & 63;
    const int qq   = lane >> 4, l15 = lane & 15;
    const int sm   = tid >> 2, sc = tid & 3;          // staging: row, 8-k chunk
    const int kofs = sc * 8;

    const int row   = m0 + sm;
    const float* rowE = ent + (size_t)e[row] * DIM;
    const float* rowH = hstate + (size_t)row * HDIM - DIM;
    const float* rowQ = rel + (size_t)q[row] * DIM - (DIM + HDIM);
    const uint4* gb = (const uint4*)(W1T + (size_t)(n0 + sm) * KTOT) + sc;

    f32x4 acc[4];
    #pragma unroll
    for (int mt = 0; mt < 4; ++mt) acc[mt] = (f32x4){0.f, 0.f, 0.f, 0.f};

    float4 pa0 = *(const float4*)(rowE + kofs);
    float4 pa1 = *(const float4*)(rowE + kofs + 4);
    uint4  pb  = gb[0];

    for (int it = 0; it < KTOT / 32; ++it) {
        ushort t8[8];
        t8[0] = f2bf(pa0.x); t8[1] = f2bf(pa0.y); t8[2] = f2bf(pa0.z); t8[3] = f2bf(pa0.w);
        t8[4] = f2bf(pa1.x); t8[5] = f2bf(pa1.y); t8[6] = f2bf(pa1.z); t8[7] = f2bf(pa1.w);
        *(uint4*)&Als[sm][sc * 8] = *(uint4*)t8;
        *(uint4*)&Bls[sm][sc * 8] = pb;
        __syncthreads();
        if (it + 1 < KTOT / 32) {
            const int kg = (it + 1) * 32 + kofs;
            const float* src = (kg < DIM) ? rowE : ((kg < DIM + HDIM) ? rowH : rowQ);
            pa0 = *(const float4*)(src + kg);
            pa1 = *(const float4*)(src + kg + 4);
            pb  = gb[(it + 1) * 4];
        }
        const bf16x8 bfrag = *(const bf16x8*)&Bls[wave * 16 + l15][qq * 8];
        #pragma unroll
        for (int mt = 0; mt < 4; ++mt) {
            const bf16x8 afrag = *(const bf16x8*)&Als[mt * 16 + l15][qq * 8];
            acc[mt] = __builtin_amdgcn_mfma_f32_16x16x32_bf16(afrag, bfrag, acc[mt], 0, 0, 0);
        }
        __syncthreads();
    }
    const int n = n0 + wave * 16 + l15;
    const float bv = b1[n];
    #pragma unroll
    for (int mt = 0; mt < 4; ++mt)
        #pragma unroll
        for (int r = 0; r < 4; ++r) {
            const int m = m0 + mt * 16 + qq * 4 + r;
            Hbf[(size_t)m * ADIM + n] = f2bf(fmaxf(acc[mt][r] + bv, 0.0f));
        }
}

// ---------------- gemm2 MFMA: X2 = Hbf @ W2T^T + b2 (fp32 out) ----------------
__global__ __launch_bounds__(256) void gemm2_mfma(
    const ushort* __restrict__ A, const ushort* __restrict__ Bt,
    const float* __restrict__ bias, float* __restrict__ Cf)
{
    __shared__ __align__(16) ushort Als[64][40];
    __shared__ __align__(16) ushort Bls[64][40];
    const int tid  = threadIdx.x;
    const int n0   = blockIdx.x * 64;
    const int m0   = blockIdx.y * 64;
    const int wave = tid >> 6, lane = tid & 63;
    const int qq   = lane >> 4, l15 = lane & 15;
    const int sm   = tid >> 2, sc = tid & 3;

    const uint4* ga = (const uint4*)(A  + (size_t)(m0 + sm) * ADIM) + sc;
    const uint4* gb = (const uint4*)(Bt + (size_t)(n0 + sm) * ADIM) + sc;

    f32x4 acc[4];
    #pragma unroll
    for (int mt = 0; mt < 4; ++mt) acc[mt] = (f32x4){0.f, 0.f, 0.f, 0.f};

    uint4 pa = ga[0], pb = gb[0];
    for (int it = 0; it < ADIM / 32; ++it) {
        *(uint4*)&Als[sm][sc * 8] = pa;
        *(uint4*)&Bls[sm][sc * 8] = pb;
        __syncthreads();
        if (it + 1 < ADIM / 32) {
            pa = ga[(it + 1) * 4];
            pb = gb[(it + 1) * 4];
        }
        const bf16x8 bfrag = *(const bf16x8*)&Bls[wave * 16 + l15][qq * 8];
        #pragma unroll
        for (int mt = 0; mt < 4; ++mt) {
            const bf16x8 afrag = *(const bf16x8*)&Als[mt * 16 + l15][qq * 8];
            acc[mt] = __builtin_amdgcn_mfma_f32_16x16x32_bf16(afrag, bfrag, acc[mt], 0, 0, 0);
        }
        __syncthreads();
    }
    const int n = n0 + wave * 16 + l15;
    const float bv = bias[n];
    #pragma unroll
    for (int mt = 0; mt < 4; ++mt)
        #pragma unroll
        for (int r = 0; r < 4; ++r) {
            const int m = m0 + mt * 16 + qq * 4 + r;
            Cf[(size_t)m * ADIM + n] = acc[mt][r] + bv;
        }
}

// ------------- scores (bf16 gathers) + masked softmax + entropy -------------
__global__ __launch_bounds__(512) void scores_kernel(
    const int* __restrict__ r_space, const int* __restrict__ e_space,
    const float* __restrict__ amask,
    const ushort* __restrict__ relbf, const ushort* __restrict__ entbf,
    const float* __restrict__ X2,
    float* __restrict__ dist_out, float* __restrict__ ent_out)
{
    const int b    = blockIdx.x;
    const int tid  = threadIdx.x;
    const int wave = tid >> 6;
    const int lane = tid & 63;

    __shared__ float xs[ADIM];
    __shared__ float sc[NACT];
    __shared__ int   ridx[NACT];
    __shared__ int   eidx[NACT];
    __shared__ float red1[8], red2[8], red3[8];

    if (tid < NACT) ridx[tid] = r_space[(size_t)b * NACT + tid];
    else            eidx[tid - NACT] = e_space[(size_t)b * NACT + tid - NACT];
    if (tid < ADIM / 4)
        ((float4*)xs)[tid] = ((const float4*)(X2 + (size_t)b * ADIM))[tid];
    __syncthreads();

    const float4 xr = ((const float4*)xs)[lane];
    const float4 xe = ((const float4*)(xs + DIM))[lane];

    const int abase = wave * 32;
    for (int a0 = abase; a0 < abase + 32; a0 += 8) {
        ushort4 rv[8], ev[8];
        #pragma unroll
        for (int i = 0; i < 8; ++i) {
            rv[i] = ((const ushort4*)relbf)[(size_t)ridx[a0 + i] * (DIM / 4) + lane];
            ev[i] = ((const ushort4*)entbf)[(size_t)eidx[a0 + i] * (DIM / 4) + lane];
        }
        float p[8];
        #pragma unroll
        for (int i = 0; i < 8; ++i) {
            p[i] = bf2f(rv[i].x) * xr.x + bf2f(rv[i].y) * xr.y
                 + bf2f(rv[i].z) * xr.z + bf2f(rv[i].w) * xr.w
                 + bf2f(ev[i].x) * xe.x + bf2f(ev[i].y) * xe.y
                 + bf2f(ev[i].z) * xe.z + bf2f(ev[i].w) * xe.w;
        }
        #pragma unroll
        for (int off = 32; off; off >>= 1) {
            #pragma unroll
            for (int i = 0; i < 8; ++i) p[i] += __shfl_xor(p[i], off);
        }
        float out = p[0];
        #pragma unroll
        for (int i = 1; i < 8; ++i) out = (lane == i) ? p[i] : out;
        if (lane < 8) sc[a0 + lane] = out;
    }
    __syncthreads();

    float s = -3.0e38f;
    if (tid < NACT) {
        const float m = amask[(size_t)b * NACT + tid];
        s = sc[tid] - (1.0f - m) * 1e31f;
    }

    float mx = s;
    #pragma unroll
    for (int off = 32; off; off >>= 1) mx = fmaxf(mx, __shfl_xor(mx, off));
    if (lane == 0) red1[wave] = mx;
    __syncthreads();
    mx = red1[0];
    #pragma unroll
    for (int w = 1; w < 8; ++w) mx = fmaxf(mx, red1[w]);

    const float ex = (tid < NACT) ? expf(s - mx) : 0.0f;
    float sum = ex;
    #pragma unroll
    for (int off = 32; off; off >>= 1) sum += __shfl_xor(sum, off);
    if (lane == 0) red2[wave] = sum;
    __syncthreads();
    sum = ((red2[0] + red2[1]) + (red2[2] + red2[3]))
        + ((red2[4] + red2[5]) + (red2[6] + red2[7]));

    const float d = ex / sum;
    if (tid < NACT) dist_out[(size_t)b * NACT + tid] = d;

    float t = (tid < NACT) ? d * logf(fmaxf(d, 1e-20f)) : 0.0f;
    #pragma unroll
    for (int off = 32; off; off >>= 1) t += __shfl_xor(t, off);
    if (lane == 0) red3[wave] = t;
    __syncthreads();
    if (tid == 0)
        ent_out[b] = -(((red3[0] + red3[1]) + (red3[2] + red3[3]))
                     + ((red3[4] + red3[5]) + (red3[6] + red3[7])));
}

extern "C" void kernel_launch(void* const* d_in, const int* in_sizes, int n_in,
                              void* d_out, int out_size, void* d_ws, size_t ws_size,
                              hipStream_t stream) {
    const int*   e       = (const int*)d_in[0];
    const int*   q       = (const int*)d_in[1];
    const float* hstate  = (const float*)d_in[2];
    const int*   r_space = (const int*)d_in[3];
    const int*   e_space = (const int*)d_in[4];
    const float* amask   = (const float*)d_in[5];
    const float* ent     = (const float*)d_in[6];
    const float* rel     = (const float*)d_in[7];
    const float* W1      = (const float*)d_in[8];
    const float* b1      = (const float*)d_in[9];
    const float* W2      = (const float*)d_in[10];
    const float* b2      = (const float*)d_in[11];

    ushort* W1T   = (ushort*)d_ws;                       // 512*1024
    ushort* W2T   = W1T   + (size_t)ADIM * KTOT;         // 512*512
    ushort* Hbf   = W2T   + (size_t)ADIM * ADIM;         // 1024*512
    ushort* entbf = Hbf   + (size_t)NB * ADIM;           // 100000*256
    ushort* relbf = entbf + (size_t)NE * DIM;            // 400*256
    float*  X2    = (float*)(relbf + (size_t)NR * DIM);  // 1024*512
    float*  dist  = (float*)d_out;
    float*  entr  = dist + (size_t)NB * NACT;

    prep_transpose<<<dim3(16, 8, 2), 256, 0, stream>>>(W1, W2, W1T, W2T);
    mega_conv_gemm1<<<CONVB + 128, 256, 0, stream>>>(
        ent, rel, hstate, e, q, W1T, b1, entbf, relbf, Hbf);
    gemm2_mfma<<<dim3(ADIM / 64, NB / 64), 256, 0, stream>>>(Hbf, W2T, b2, X2);
    scores_kernel<<<NB, 512, 0, stream>>>(
        r_space, e_space, amask, relbf, entbf, X2, dist, entr);
}